// Round 1
// baseline (314.590 us; speedup 1.0000x reference)
//
#include <hip/hip_runtime.h>
#include <stdint.h>

#define D_DIM 128
#define NROW 8192
#define MROW 8192
#define TILE 128
#define LDK 136      // bf16 elems per LDS row (128 + 8 pad) -> 272 B, 16B-aligned rows
#define TLD 68       // f32 words per row of transpose buffer (64 + 4 pad) -> 272 B
#define OUT_LD 8192

typedef __bf16 bf16x8 __attribute__((ext_vector_type(8)));
typedef float f32x4 __attribute__((ext_vector_type(4)));

union SMem {
    struct {
        unsigned short Xs[TILE][LDK];   // 34816 B
        unsigned short Ys[TILE][LDK];   // 34816 B
    } st;                               // 69632 B
    float tr[4][64 * TLD];              // 4 * 17408 B = 69632 B (per-wave transpose)
};

__device__ __forceinline__ unsigned short f32_to_bf16(float f) {
    uint32_t u = __float_as_uint(f);
    u = (u + 0x7FFFu + ((u >> 16) & 1u)) >> 16;   // round-to-nearest-even
    return (unsigned short)u;
}

// Exact f32 row norms: one wave per row, X rows then Y rows, into d_ws.
__global__ __launch_bounds__(256) void rbf_norms(const float* __restrict__ X,
                                                 const float* __restrict__ Y,
                                                 float* __restrict__ nrm) {
    const int t = threadIdx.x;
    const int w = t >> 6, lane = t & 63;
    const int rid = blockIdx.x * 4 + w;
    const float* src = (rid < NROW) ? (X + (size_t)rid * D_DIM)
                                    : (Y + (size_t)(rid - NROW) * D_DIM);
    float2 v = *(const float2*)(src + 2 * lane);
    float s = v.x * v.x + v.y * v.y;
    #pragma unroll
    for (int off = 32; off > 0; off >>= 1) s += __shfl_xor(s, off, 64);
    if (lane == 0) nrm[rid] = s;
}

__global__ __launch_bounds__(256) void rbf_main(const float* __restrict__ X,
                                                const float* __restrict__ Y,
                                                const float* __restrict__ sigma,
                                                const float* __restrict__ nrm,
                                                float* __restrict__ out) {
    __shared__ SMem sm;
    __shared__ float x2s[TILE];
    __shared__ float y2s[TILE];

    const int t = threadIdx.x;
    const int row0 = blockIdx.y * TILE;   // rows of out (X rows)
    const int col0 = blockIdx.x * TILE;   // cols of out (Y rows)

    if (t < 128) x2s[t] = nrm[row0 + t];
    else         y2s[t - 128] = nrm[NROW + col0 + (t - 128)];

    // Stage 128x128 f32 tiles of X and Y, converting to bf16 in LDS.
    // 4096 float4 per tile; thread t, iter i handles float4 #(t + 256*i).
    #pragma unroll 4
    for (int i = 0; i < 16; ++i) {
        int f = t + 256 * i;
        int r = f >> 5;            // tile row 0..127
        int q = (f & 31) * 4;      // k offset 0..124, step 4
        float4 vx = *(const float4*)(X + (size_t)(row0 + r) * D_DIM + q);
        float4 vy = *(const float4*)(Y + (size_t)(col0 + r) * D_DIM + q);
        ushort4 hx = { f32_to_bf16(vx.x), f32_to_bf16(vx.y), f32_to_bf16(vx.z), f32_to_bf16(vx.w) };
        ushort4 hy = { f32_to_bf16(vy.x), f32_to_bf16(vy.y), f32_to_bf16(vy.z), f32_to_bf16(vy.w) };
        *(ushort4*)(&sm.st.Xs[r][q]) = hx;
        *(ushort4*)(&sm.st.Ys[r][q]) = hy;
    }
    __syncthreads();

    const int w = t >> 6, ln = t & 63;
    const int quad = ln >> 4, l16 = ln & 15;
    const int wr = (w >> 1) * 64;   // wave's 64x64 quadrant
    const int wc = (w & 1) * 64;

    f32x4 acc[4][4] = {};
    // K = 128 = 4 steps of 32. A[m=lane&15][k=quad*8+j], B[k=quad*8+j][n=lane&15].
    #pragma unroll
    for (int ks = 0; ks < 4; ++ks) {
        const int k = ks * 32 + quad * 8;
        bf16x8 a[4], b[4];
        #pragma unroll
        for (int ti = 0; ti < 4; ++ti)
            a[ti] = *(const bf16x8*)(&sm.st.Xs[wr + ti * 16 + l16][k]);
        #pragma unroll
        for (int tj = 0; tj < 4; ++tj)
            b[tj] = *(const bf16x8*)(&sm.st.Ys[wc + tj * 16 + l16][k]);
        #pragma unroll
        for (int ti = 0; ti < 4; ++ti)
            #pragma unroll
            for (int tj = 0; tj < 4; ++tj)
                acc[ti][tj] = __builtin_amdgcn_mfma_f32_16x16x32_bf16(a[ti], b[tj], acc[ti][tj], 0, 0, 0);
    }

    const float s2 = sigma[0] * sigma[0] + 1e-9f;
    const float cexp = -1.4426950408889634f / s2;   // exp(-d/s2) = exp2(d * cexp)

    __syncthreads();   // all waves done reading Xs/Ys; safe to alias as tr
    float* tw = sm.tr[w];
    // C/D layout (verified m89/m91): col = lane&15, row = quad*4 + reg.
    #pragma unroll
    for (int ti = 0; ti < 4; ++ti)
        #pragma unroll
        for (int tj = 0; tj < 4; ++tj)
            #pragma unroll
            for (int r = 0; r < 4; ++r) {
                int lr = ti * 16 + quad * 4 + r;   // 0..63 within quadrant
                int lc = tj * 16 + l16;            // 0..63
                float d = x2s[wr + lr] + y2s[wc + lc] - 2.0f * acc[ti][tj][r];
                tw[lr * TLD + lc] = exp2f(d * cexp);
            }
    __syncthreads();   // write->read fence (also keeps waves' regions clean)

    // Coalesced write-out: each lane stores a float4 (16 lanes = 256 B contiguous).
    #pragma unroll 4
    for (int i = 0; i < 16; ++i) {
        int lr = i * 4 + quad;
        f32x4 v = *(const f32x4*)(&tw[lr * TLD + l16 * 4]);
        size_t grow = (size_t)(row0 + wr + lr);
        size_t gcol = (size_t)(col0 + wc + l16 * 4);
        *(f32x4*)(out + grow * OUT_LD + gcol) = v;
    }
}

extern "C" void kernel_launch(void* const* d_in, const int* in_sizes, int n_in,
                              void* d_out, int out_size, void* d_ws, size_t ws_size,
                              hipStream_t stream) {
    const float* X = (const float*)d_in[0];
    const float* Y = (const float*)d_in[1];
    const float* sigma = (const float*)d_in[2];
    float* nrm = (float*)d_ws;          // 16384 f32 = 64 KB scratch
    float* out = (float*)d_out;

    rbf_norms<<<(NROW + MROW) / 4, 256, 0, stream>>>(X, Y, nrm);
    rbf_main<<<dim3(MROW / TILE, NROW / TILE), 256, 0, stream>>>(X, Y, sigma, nrm, out);
}

// Round 2
// 309.165 us; speedup vs baseline: 1.0175x; 1.0175x over previous
//
#include <hip/hip_runtime.h>
#include <stdint.h>

#define D_DIM 128
#define NROW 8192
#define MROW 8192
#define TILE 128
#define LDK2 72      // shorts per LDS row for a K=64 chunk (64 data + 8 pad) = 144 B, 16B-multiple
#define OUT_LD 8192

typedef __bf16 bf16x8 __attribute__((ext_vector_type(8)));
typedef float f32x4 __attribute__((ext_vector_type(4)));

__device__ __forceinline__ unsigned short f32_to_bf16(float f) {
    uint32_t u = __float_as_uint(f);
    u = (u + 0x7FFFu + ((u >> 16) & 1u)) >> 16;   // round-to-nearest-even
    return (unsigned short)u;
}

// Exact f32 row norms: one wave per row, X rows then Y rows, into d_ws.
__global__ __launch_bounds__(256) void rbf_norms(const float* __restrict__ X,
                                                 const float* __restrict__ Y,
                                                 float* __restrict__ nrm) {
    const int t = threadIdx.x;
    const int w = t >> 6, lane = t & 63;
    const int rid = blockIdx.x * 4 + w;
    const float* src = (rid < NROW) ? (X + (size_t)rid * D_DIM)
                                    : (Y + (size_t)(rid - NROW) * D_DIM);
    float2 v = *(const float2*)(src + 2 * lane);
    float s = v.x * v.x + v.y * v.y;
    #pragma unroll
    for (int off = 32; off > 0; off >>= 1) s += __shfl_xor(s, off, 64);
    if (lane == 0) nrm[rid] = s;
}

// 128x128 output tile per block. Two K=64 staging phases (38 KB LDS -> 4 blocks/CU).
// MFMA computes the TRANSPOSED tile (A=Y frag, B=X frag) so the 4 acc regs of each
// 16x16 tile are 4 consecutive output COLUMNS for a fixed row -> direct dwordx4 stores.
__global__ __launch_bounds__(256, 4) void rbf_main(const float* __restrict__ X,
                                                   const float* __restrict__ Y,
                                                   const float* __restrict__ sigma,
                                                   const float* __restrict__ nrm,
                                                   float* __restrict__ out) {
    __shared__ unsigned short Xs[TILE][LDK2];   // 18432 B
    __shared__ unsigned short Ys[TILE][LDK2];   // 18432 B
    __shared__ float x2s[TILE];
    __shared__ float y2s[TILE];

    const int t = threadIdx.x;
    const int row0 = blockIdx.y * TILE;   // X rows (out rows)
    const int col0 = blockIdx.x * TILE;   // Y rows (out cols)

    if (t < 128) x2s[t] = nrm[row0 + t];
    else         y2s[t - 128] = nrm[NROW + col0 + (t - 128)];

    const int w = t >> 6, ln = t & 63;
    const int quad = ln >> 4, l16 = ln & 15;
    const int wr = (w >> 1) * 64;   // X-dim half of the tile for this wave
    const int wc = (w & 1) * 64;    // Y-dim half

    f32x4 acc[4][4] = {};   // [ti = X-dim 16-frag][tj = Y-dim 16-frag]

    #pragma unroll
    for (int p = 0; p < 2; ++p) {
        // Stage 128 rows x 64 k of X and Y (f32 -> bf16 into LDS).
        #pragma unroll
        for (int i = 0; i < 8; ++i) {
            int f = t + 256 * i;
            int r = f >> 4;            // tile row 0..127
            int c = (f & 15) * 4;      // k offset within chunk, 0..60 step 4
            float4 vx = *(const float4*)(X + (size_t)(row0 + r) * D_DIM + p * 64 + c);
            float4 vy = *(const float4*)(Y + (size_t)(col0 + r) * D_DIM + p * 64 + c);
            ushort4 hx = { f32_to_bf16(vx.x), f32_to_bf16(vx.y), f32_to_bf16(vx.z), f32_to_bf16(vx.w) };
            ushort4 hy = { f32_to_bf16(vy.x), f32_to_bf16(vy.y), f32_to_bf16(vy.z), f32_to_bf16(vy.w) };
            *(ushort4*)(&Xs[r][c]) = hx;
            *(ushort4*)(&Ys[r][c]) = hy;
        }
        __syncthreads();

        #pragma unroll
        for (int ks = 0; ks < 2; ++ks) {
            const int k = ks * 32 + quad * 8;
            bf16x8 ax[4], by[4];
            #pragma unroll
            for (int ti = 0; ti < 4; ++ti)
                ax[ti] = *(const bf16x8*)(&Xs[wr + ti * 16 + l16][k]);
            #pragma unroll
            for (int tj = 0; tj < 4; ++tj)
                by[tj] = *(const bf16x8*)(&Ys[wc + tj * 16 + l16][k]);
            #pragma unroll
            for (int ti = 0; ti < 4; ++ti)
                #pragma unroll
                for (int tj = 0; tj < 4; ++tj)
                    // A = Y frag (rows = out cols), B = X frag (cols = out rows)
                    acc[ti][tj] = __builtin_amdgcn_mfma_f32_16x16x32_bf16(by[tj], ax[ti], acc[ti][tj], 0, 0, 0);
        }
        if (p == 0) __syncthreads();   // phase-0 reads done before phase-1 restage
    }

    const float s2 = sigma[0] * sigma[0] + 1e-9f;
    const float cexp = -1.4426950408889634f / s2;   // exp(-d/s2) = exp2(d * cexp)

    // D layout: col(n) = l16 -> X row; row(m) = quad*4 + r -> Y row (out column).
    float x2r[4];
    #pragma unroll
    for (int ti = 0; ti < 4; ++ti) x2r[ti] = x2s[wr + ti * 16 + l16];

    #pragma unroll
    for (int tj = 0; tj < 4; ++tj) {
        f32x4 y2v = *(const f32x4*)(&y2s[wc + tj * 16 + quad * 4]);
        size_t gcol = (size_t)(col0 + wc + tj * 16 + quad * 4);
        #pragma unroll
        for (int ti = 0; ti < 4; ++ti) {
            f32x4 v;
            #pragma unroll
            for (int r = 0; r < 4; ++r) {
                float d = x2r[ti] + y2v[r] - 2.0f * acc[ti][tj][r];
                v[r] = __builtin_amdgcn_exp2f(d * cexp);
            }
            size_t grow = (size_t)(row0 + wr + ti * 16 + l16);
            __builtin_nontemporal_store(v, (f32x4*)(out + grow * OUT_LD + gcol));
        }
    }
}

extern "C" void kernel_launch(void* const* d_in, const int* in_sizes, int n_in,
                              void* d_out, int out_size, void* d_ws, size_t ws_size,
                              hipStream_t stream) {
    const float* X = (const float*)d_in[0];
    const float* Y = (const float*)d_in[1];
    const float* sigma = (const float*)d_in[2];
    float* nrm = (float*)d_ws;          // 16384 f32 = 64 KB scratch
    float* out = (float*)d_out;

    rbf_norms<<<(NROW + MROW) / 4, 256, 0, stream>>>(X, Y, nrm);
    rbf_main<<<dim3(MROW / TILE, NROW / TILE), 256, 0, stream>>>(X, Y, sigma, nrm, out);
}